// Round 7
// baseline (246.784 us; speedup 1.0000x reference)
//
#include <hip/hip_runtime.h>
#include <cstdint>
#include <cstddef>

#define NP  1024
#define FD  10
#define BSZ 128
#define TPB 64
#define RPT 16   // rows per lane: 64 lanes x 16 = 1024 rows per (pair,dir) block

typedef float v2f __attribute__((ext_vector_type(2)));
typedef float v4f __attribute__((ext_vector_type(4)));

#define SHUF2(v, a, b) __builtin_shufflevector((v), (v), (a), (b))

// v_pk_fma_f32 with src0 broadcast from one word of an aligned VGPR pair.
// lo: both result halves use src0's low word; hi: both use the high word.
// src1/src2 are normal packed [lo,hi]. (VOP3P, gfx90a+; present on gfx950.)
static __device__ __forceinline__ v2f pk_fma_lo(v2f a, v2f b, v2f c) {
    v2f d;
    asm("v_pk_fma_f32 %0, %1, %2, %3 op_sel:[0,0,0] op_sel_hi:[0,1,1]"
        : "=v"(d) : "v"(a), "v"(b), "v"(c));
    return d;
}
static __device__ __forceinline__ v2f pk_fma_hi(v2f a, v2f b, v2f c) {
    v2f d;
    asm("v_pk_fma_f32 %0, %1, %2, %3 op_sel:[1,0,0] op_sel_hi:[1,1,1]"
        : "=v"(d) : "v"(a), "v"(b), "v"(c));
    return d;
}

// One block = one wave = one (pair, dir). bid = pair*2 + d.
//   d=0: rows = state(ag), cols = goal(dg)   (reward_s2g)
//   d=1: rows = goal(dg),  cols = state(ag)  (reward_g2s)
// Shift-reduced distance: argmin_m [rs + cs_m - 2 r.c_m] == argmin_m [cs_m + r.c2_m],
// c2 = -2*c staged in LDS as component-planar arrays (natural v_pk pair layout).
// Tracker keeps the winning 8-col block; exact first-tie index is recovered by
// replaying the identical fmaf chain from global (bit-exact vs the staged values).
extern "C" __global__ __launch_bounds__(TPB)
void chamfer_pairs(const float* __restrict__ ag, const float* __restrict__ dg,
                   const float* __restrict__ nmean, const float* __restrict__ nstd,
                   float* __restrict__ out /* [BSZ], pre-zeroed */)
{
    __shared__ __align__(16) float cxF[NP];
    __shared__ __align__(16) float cyF[NP];
    __shared__ __align__(16) float czF[NP];
    __shared__ __align__(16) float cwF[NP];
    __shared__ __align__(16) float csF[NP];

    const int bid  = blockIdx.x;        // 0..1023
    const int pair = bid >> 1;
    const int d    = bid & 1;
    const int tid  = threadIdx.x;

    const float* rowsrc = ((d == 0) ? ag : dg) + (size_t)pair * (NP * FD);
    const float* colsrc = ((d == 0) ? dg : ag) + (size_t)pair * (NP * FD);

    // Column-side constants: -2 * (std, mean) for features 5..8.
    const float s5 = -2.0f * nstd[5], m5 = -2.0f * nmean[5];
    const float s6 = -2.0f * nstd[6], m6 = -2.0f * nmean[6];
    const float s7 = -2.0f * nstd[7], m7 = -2.0f * nmean[7];
    const float s8 = -2.0f * nstd[8], m8 = -2.0f * nmean[8];
    // Row-side (positive) constants; -0.5*fmaf(p,-2s,-2m) == fmaf(p,s,m) bit-exactly.
    const float p5 = nstd[5], q5 = nmean[5];
    const float p6 = nstd[6], q6 = nmean[6];
    const float p7 = nstd[7], q7 = nmean[7];
    const float p8 = nstd[8], q8 = nmean[8];
    const float std0 = nstd[0], mean0 = nmean[0];
    const float std1 = nstd[1], mean1 = nmean[1];

    // ---- Stage columns into LDS (component-planar): t = fmaf(raw,-2s,-2m),
    //      cs = 0.25*dot(t,t)  (same op order as rounds 3-6).
    for (int m = tid; m < NP; m += TPB) {
        const float* p = colsrc + (size_t)m * FD;
        float t0 = fmaf(p[5], s5, m5);
        float t1 = fmaf(p[6], s6, m6);
        float t2 = fmaf(p[7], s7, m7);
        float t3 = fmaf(p[8], s8, m8);
        cxF[m] = t0; cyF[m] = t1; czF[m] = t2; cwF[m] = t3;
        csF[m] = 0.25f * (t0 * t0 + t1 * t1 + t2 * t2 + t3 * t3);
    }

    // ---- Rows in registers: rv = normalized row vis (positive route).
    v2f  rxy[RPT];   // {x, y}
    v2f  rzw[RPT];   // {z, w}
    float bestd[RPT];
    int   bblk[RPT];
#pragma unroll
    for (int r = 0; r < RPT; ++r) {
        int n = tid + TPB * r;
        const float* p = rowsrc + (size_t)n * FD;
        float a0 = fmaf(p[5], p5, q5);
        float a1 = fmaf(p[6], p6, q6);
        float a2 = fmaf(p[7], p7, q7);
        float a3 = fmaf(p[8], p8, q8);
        rxy[r].x = a0; rxy[r].y = a1;
        rzw[r].x = a2; rzw[r].y = a3;
        bestd[r] = 3.0e38f;
        bblk[r]  = 0;
    }
    __syncthreads();

    const v4f* X4 = (const v4f*)cxF;
    const v4f* Y4 = (const v4f*)cyF;
    const v4f* Z4 = (const v4f*)czF;
    const v4f* W4 = (const v4f*)cwF;
    const v4f* S4 = (const v4f*)csF;

    // ---- Main loop: 8 columns/iter, wave-uniform b128 broadcasts, packed fma.
    for (int g = 0; g < NP / 8; ++g) {
        const int m = g * 8;
        v4f xA = X4[2 * g], xB = X4[2 * g + 1];
        v4f yA = Y4[2 * g], yB = Y4[2 * g + 1];
        v4f zA = Z4[2 * g], zB = Z4[2 * g + 1];
        v4f wA = W4[2 * g], wB = W4[2 * g + 1];
        v4f cA = S4[2 * g], cB = S4[2 * g + 1];
        v2f x0 = SHUF2(xA, 0, 1), x1 = SHUF2(xA, 2, 3), x2 = SHUF2(xB, 0, 1), x3 = SHUF2(xB, 2, 3);
        v2f y0 = SHUF2(yA, 0, 1), y1 = SHUF2(yA, 2, 3), y2 = SHUF2(yB, 0, 1), y3 = SHUF2(yB, 2, 3);
        v2f z0 = SHUF2(zA, 0, 1), z1 = SHUF2(zA, 2, 3), z2 = SHUF2(zB, 0, 1), z3 = SHUF2(zB, 2, 3);
        v2f w0 = SHUF2(wA, 0, 1), w1 = SHUF2(wA, 2, 3), w2 = SHUF2(wB, 0, 1), w3 = SHUF2(wB, 2, 3);
        v2f c0 = SHUF2(cA, 0, 1), c1 = SHUF2(cA, 2, 3), c2 = SHUF2(cB, 0, 1), c3 = SHUF2(cB, 2, 3);
#pragma unroll
        for (int r = 0; r < RPT; ++r) {
            // per-element chain identical to the replay: fma(x),fma(y),fma(z),fma(w) from cs
            v2f u0 = pk_fma_lo(rxy[r], x0, c0);
            u0 = pk_fma_hi(rxy[r], y0, u0);
            u0 = pk_fma_lo(rzw[r], z0, u0);
            u0 = pk_fma_hi(rzw[r], w0, u0);
            v2f u1 = pk_fma_lo(rxy[r], x1, c1);
            u1 = pk_fma_hi(rxy[r], y1, u1);
            u1 = pk_fma_lo(rzw[r], z1, u1);
            u1 = pk_fma_hi(rzw[r], w1, u1);
            v2f u2 = pk_fma_lo(rxy[r], x2, c2);
            u2 = pk_fma_hi(rxy[r], y2, u2);
            u2 = pk_fma_lo(rzw[r], z2, u2);
            u2 = pk_fma_hi(rzw[r], w2, u2);
            v2f u3 = pk_fma_lo(rxy[r], x3, c3);
            u3 = pk_fma_hi(rxy[r], y3, u3);
            u3 = pk_fma_lo(rzw[r], z3, u3);
            u3 = pk_fma_hi(rzw[r], w3, u3);
            // exact min over 8 (value order-invariant; no NaNs)
            float bm = fminf(fminf(fminf(u0.x, u0.y), fminf(u1.x, u1.y)),
                             fminf(fminf(u2.x, u2.y), fminf(u3.x, u3.y)));
            bool lt = bm < bestd[r];       // strict < keeps FIRST block on ties
            bestd[r] = fminf(bestd[r], bm);
            bblk[r]  = lt ? m : bblk[r];
        }
    }

    // ---- Epilogue: replay winning block from GLOBAL (bit-exact chain; keeps
    // the LDS pipe clean), recover first-tie index, accumulate xy L2 distance.
    float sum = 0.0f;
#pragma unroll
    for (int r = 0; r < RPT; ++r) {
        int n  = tid + TPB * r;
        int mb = bblk[r];
        float vx = rxy[r].x, vy = rxy[r].y, vz = rzw[r].x, vw = rzw[r].y;
        float dd[8];
#pragma unroll
        for (int j = 0; j < 8; ++j) {
            const float* p = colsrc + (size_t)(mb + j) * FD;
            float t0 = fmaf(p[5], s5, m5);
            float t1 = fmaf(p[6], s6, m6);
            float t2 = fmaf(p[7], s7, m7);
            float t3 = fmaf(p[8], s8, m8);
            float cs = 0.25f * (t0 * t0 + t1 * t1 + t2 * t2 + t3 * t3);
            float t = fmaf(vx, t0, cs);
            t = fmaf(vy, t1, t);
            t = fmaf(vz, t2, t);
            t = fmaf(vw, t3, t);
            dd[j] = t;
        }
        int sel = 0;
#pragma unroll
        for (int j = 7; j >= 0; --j)       // descending: smallest j wins ties
            if (dd[j] == bestd[r]) sel = j;
        int idx = mb + sel;

        const float* pc = colsrc + (size_t)idx * FD;
        float gx = fmaf(pc[0], std0, mean0);
        float gy = fmaf(pc[1], std1, mean1);
        const float* pr = rowsrc + (size_t)n * FD;
        float ax = fmaf(pr[0], std0, mean0);
        float ay = fmaf(pr[1], std1, mean1);
        float dx = ax - gx;
        float dy = ay - gy;
        float dist = sqrtf(dx * dx + dy * dy);
        float rss = vx * vx + vy * vy + vz * vz + vw * vw;   // == 0.25*dot(t,t) bit-exactly
        if (bestd[r] > 6.0f - rss) dist = 1.0f;  // min_d > LATENT_DIST_THRESHOLD
        sum += dist;
    }

    // ---- Single-wave reduce, one atomic per block.
    for (int o = 32; o > 0; o >>= 1) sum += __shfl_down(sum, o, 64);
    if (tid == 0) {
        // out[b] = -(sum over 4 views x 2 dirs x 1024 rows) / 8192
        atomicAdd(&out[bid >> 3], sum * (-1.0f / 8192.0f));
    }
}

extern "C" void kernel_launch(void* const* d_in, const int* in_sizes, int n_in,
                              void* d_out, int out_size, void* d_ws, size_t ws_size,
                              hipStream_t stream)
{
    const float* ag = (const float*)d_in[0];   // achieved_goal (128,4,1024,10)
    const float* dg = (const float*)d_in[1];   // desired_goal  (128,4,1024,10)
    const float* nm = (const float*)d_in[2];   // norm_mean (10,)
    const float* ns = (const float*)d_in[3];   // norm_std  (10,)

    hipMemsetAsync(d_out, 0, BSZ * sizeof(float), stream);   // out is accumulated
    chamfer_pairs<<<BSZ * 4 * 2, TPB, 0, stream>>>(ag, dg, nm, ns, (float*)d_out);
}

// Round 8
// 207.924 us; speedup vs baseline: 1.1869x; 1.1869x over previous
//
#include <hip/hip_runtime.h>
#include <cstdint>
#include <cstddef>

#define NP  1024
#define FD  10
#define BSZ 128
#define TPB 128
#define RPT 8    // rows per lane: 128 threads x 8 = 1024 rows per (pair,dir) block

// One block per (pair, dir): bid = pair*2 + d.
//   d=0: rows = state(ag), cols = goal(dg)   (reward_s2g)
//   d=1: rows = goal(dg),  cols = state(ag)  (reward_g2s)
// Shift-reduced distance: argmin_m [rs + cs_m - 2 r.c_m] == argmin_m [cs_m + r.c2_m],
// c2 = -2*c staged in LDS (interleaved float4 -> b128 loads). Tracker keeps the
// winning 8-col block; exact first-tie index is recovered by replaying the
// identical fmaf chain from GLOBAL (recompute of the staging chain is
// bit-identical, and keeps the LDS pipe free of divergent reads).
extern "C" __global__ __launch_bounds__(TPB, 2)
void chamfer_pairs(const float* __restrict__ ag, const float* __restrict__ dg,
                   const float* __restrict__ nmean, const float* __restrict__ nstd,
                   float* __restrict__ out /* [BSZ], pre-zeroed */)
{
    __shared__ __align__(16) float4 cvis[NP];   // -2 * normalized col vis (16 KB)
    __shared__ __align__(16) float  csh[NP];    // ||col vis||^2            (4 KB)
    __shared__ float red[TPB / 64];

    const int bid  = blockIdx.x;        // 0..1023
    const int pair = bid >> 1;
    const int d    = bid & 1;
    const int tid  = threadIdx.x;

    const float* rowsrc = ((d == 0) ? ag : dg) + (size_t)pair * (NP * FD);
    const float* colsrc = ((d == 0) ? dg : ag) + (size_t)pair * (NP * FD);

    // -2*(std, mean) for vis features 5..8 (uniform -> scalar regs).
    const float s5 = -2.0f * nstd[5], m5 = -2.0f * nmean[5];
    const float s6 = -2.0f * nstd[6], m6 = -2.0f * nmean[6];
    const float s7 = -2.0f * nstd[7], m7 = -2.0f * nmean[7];
    const float s8 = -2.0f * nstd[8], m8 = -2.0f * nmean[8];
    const float std0 = nstd[0], mean0 = nmean[0];
    const float std1 = nstd[1], mean1 = nmean[1];

    // ---- Stage columns into LDS: t = fmaf(raw, -2s, -2m); cs = 0.25*dot(t,t)
    //      (exact chain from rounds 3-6; b128 stores, conflict-light).
    for (int m = tid; m < NP; m += TPB) {
        const float* p = colsrc + (size_t)m * FD;
        float t0 = fmaf(p[5], s5, m5);
        float t1 = fmaf(p[6], s6, m6);
        float t2 = fmaf(p[7], s7, m7);
        float t3 = fmaf(p[8], s8, m8);
        cvis[m] = make_float4(t0, t1, t2, t3);
        csh[m]  = 0.25f * (t0 * t0 + t1 * t1 + t2 * t2 + t3 * t3);
    }

    // ---- Rows in registers via the proven -0.5*t route (bit-exact lineage).
    float4 rv[RPT];
    float  rthr[RPT];
    float  bestd[RPT];
    int    bblk[RPT];
#pragma unroll
    for (int r = 0; r < RPT; ++r) {
        int n = tid + TPB * r;
        const float* p = rowsrc + (size_t)n * FD;
        float t0 = fmaf(p[5], s5, m5);
        float t1 = fmaf(p[6], s6, m6);
        float t2 = fmaf(p[7], s7, m7);
        float t3 = fmaf(p[8], s8, m8);
        rv[r] = make_float4(-0.5f * t0, -0.5f * t1, -0.5f * t2, -0.5f * t3);
        float rss = 0.25f * (t0 * t0 + t1 * t1 + t2 * t2 + t3 * t3);
        rthr[r] = 6.0f - rss;            // (rs + bestd') > 6  <=>  bestd' > 6 - rs
        bestd[r] = 3.0e38f;
        bblk[r]  = 0;
    }
    __syncthreads();

    // ---- Main loop: 8 columns/iter, 10 wave-uniform b128 broadcasts, R3 chain.
    for (int g = 0; g < NP / 8; ++g) {
        const int m = g * 8;
        float4 c0 = cvis[m + 0];
        float4 c1 = cvis[m + 1];
        float4 c2 = cvis[m + 2];
        float4 c3 = cvis[m + 3];
        float4 c4 = cvis[m + 4];
        float4 c5 = cvis[m + 5];
        float4 c6 = cvis[m + 6];
        float4 c7 = cvis[m + 7];
        float4 csA = *(const float4*)(csh + m);
        float4 csB = *(const float4*)(csh + m + 4);
#pragma unroll
        for (int r = 0; r < RPT; ++r) {
            float4 v = rv[r];
            float d0 = fmaf(v.x, c0.x, csA.x); d0 = fmaf(v.y, c0.y, d0); d0 = fmaf(v.z, c0.z, d0); d0 = fmaf(v.w, c0.w, d0);
            float d1 = fmaf(v.x, c1.x, csA.y); d1 = fmaf(v.y, c1.y, d1); d1 = fmaf(v.z, c1.z, d1); d1 = fmaf(v.w, c1.w, d1);
            float d2 = fmaf(v.x, c2.x, csA.z); d2 = fmaf(v.y, c2.y, d2); d2 = fmaf(v.z, c2.z, d2); d2 = fmaf(v.w, c2.w, d2);
            float d3 = fmaf(v.x, c3.x, csA.w); d3 = fmaf(v.y, c3.y, d3); d3 = fmaf(v.z, c3.z, d3); d3 = fmaf(v.w, c3.w, d3);
            float d4 = fmaf(v.x, c4.x, csB.x); d4 = fmaf(v.y, c4.y, d4); d4 = fmaf(v.z, c4.z, d4); d4 = fmaf(v.w, c4.w, d4);
            float d5 = fmaf(v.x, c5.x, csB.y); d5 = fmaf(v.y, c5.y, d5); d5 = fmaf(v.z, c5.z, d5); d5 = fmaf(v.w, c5.w, d5);
            float d6 = fmaf(v.x, c6.x, csB.z); d6 = fmaf(v.y, c6.y, d6); d6 = fmaf(v.z, c6.z, d6); d6 = fmaf(v.w, c6.w, d6);
            float d7 = fmaf(v.x, c7.x, csB.w); d7 = fmaf(v.y, c7.y, d7); d7 = fmaf(v.z, c7.z, d7); d7 = fmaf(v.w, c7.w, d7);
            // exact min of 8 (value order-invariant; no NaNs) -> v_min3 friendly
            float p0 = fminf(fminf(d0, d1), d2);
            float p1 = fminf(fminf(d3, d4), d5);
            float p2 = fminf(d6, d7);
            float bm = fminf(fminf(p0, p1), p2);
            bool lt = bm < bestd[r];       // strict < keeps FIRST block on ties
            bestd[r] = fminf(bestd[r], bm);
            bblk[r]  = lt ? m : bblk[r];
        }
    }

    // ---- Epilogue: replay winning block from GLOBAL (staging chain recompute
    // is bit-identical to the LDS contents), recover first-tie index, gather xy.
    float sum = 0.0f;
#pragma unroll
    for (int r = 0; r < RPT; ++r) {
        int n  = tid + TPB * r;
        int mb = bblk[r];
        float4 v = rv[r];
        float dd[8];
#pragma unroll
        for (int j = 0; j < 8; ++j) {
            const float* p = colsrc + (size_t)(mb + j) * FD;
            float t0 = fmaf(p[5], s5, m5);
            float t1 = fmaf(p[6], s6, m6);
            float t2 = fmaf(p[7], s7, m7);
            float t3 = fmaf(p[8], s8, m8);
            float cs = 0.25f * (t0 * t0 + t1 * t1 + t2 * t2 + t3 * t3);
            float t = fmaf(v.x, t0, cs);
            t = fmaf(v.y, t1, t);
            t = fmaf(v.z, t2, t);
            t = fmaf(v.w, t3, t);
            dd[j] = t;
        }
        int sel = 0;
#pragma unroll
        for (int j = 7; j >= 0; --j)       // descending: smallest j wins ties
            if (dd[j] == bestd[r]) sel = j;
        int idx = mb + sel;

        const float* pc = colsrc + (size_t)idx * FD;
        float gx = fmaf(pc[0], std0, mean0);
        float gy = fmaf(pc[1], std1, mean1);
        const float* pr = rowsrc + (size_t)n * FD;
        float ax = fmaf(pr[0], std0, mean0);
        float ay = fmaf(pr[1], std1, mean1);
        float dx = ax - gx;
        float dy = ay - gy;
        float dist = sqrtf(dx * dx + dy * dy);
        if (bestd[r] > rthr[r]) dist = 1.0f;   // min_d > LATENT_DIST_THRESHOLD
        sum += dist;
    }

    // ---- Reduce: wave shuffle, cross-wave LDS, one atomic per block.
    for (int o = 32; o > 0; o >>= 1) sum += __shfl_down(sum, o, 64);
    if ((tid & 63) == 0) red[tid >> 6] = sum;
    __syncthreads();
    if (tid == 0) {
        float s = red[0] + red[1];
        // out[b] = -(sum over 4 views x 2 dirs x 1024 rows) / 8192
        atomicAdd(&out[bid >> 3], s * (-1.0f / 8192.0f));
    }
}

extern "C" void kernel_launch(void* const* d_in, const int* in_sizes, int n_in,
                              void* d_out, int out_size, void* d_ws, size_t ws_size,
                              hipStream_t stream)
{
    const float* ag = (const float*)d_in[0];   // achieved_goal (128,4,1024,10)
    const float* dg = (const float*)d_in[1];   // desired_goal  (128,4,1024,10)
    const float* nm = (const float*)d_in[2];   // norm_mean (10,)
    const float* ns = (const float*)d_in[3];   // norm_std  (10,)

    hipMemsetAsync(d_out, 0, BSZ * sizeof(float), stream);   // out is accumulated
    chamfer_pairs<<<BSZ * 4 * 2, TPB, 0, stream>>>(ag, dg, nm, ns, (float*)d_out);
}